// Round 2
// baseline (326.299 us; speedup 1.0000x reference)
//
#include <hip/hip_runtime.h>
#include <math.h>
#include <stdint.h>
#include <stddef.h>

// ProbSparse multi-head attention (Informer-style), fp32, MI355X.
// Heads share q,k,v; only the threefry-sampled key set differs per head.
// S (the shared 2x1024x1024 score matrix) lives in d_out and is consumed
// before k_out overwrites d_out with the final result.

#define BB     2
#define LQ     1024
#define LK     1024
#define DH     64
#define NH     16
#define DM     1024
#define USEL   34
#define USAMP  7097

// JAX >= 0.4.36 defaults jax_threefry_partitionable=True (typed keys used in
// reference). Flip to 0 if validation shows errors confined to whole rows.
#define THREEFRY_PARTITIONABLE 1

// ---------------- threefry2x32 (matches jax._src.prng) ----------------
__device__ __forceinline__ uint32_t rotl32(uint32_t x, int d) {
  return (x << d) | (x >> (32 - d));
}

__device__ __forceinline__ void threefry2x32(uint32_t k0, uint32_t k1,
                                             uint32_t x0, uint32_t x1,
                                             uint32_t& o0, uint32_t& o1) {
  uint32_t ks2 = k0 ^ k1 ^ 0x1BD11BDAu;
  x0 += k0; x1 += k1;
#define TFR(r) { x0 += x1; x1 = rotl32(x1, (r)); x1 ^= x0; }
  TFR(13) TFR(15) TFR(26) TFR(6)
  x0 += k1; x1 += ks2 + 1u;
  TFR(17) TFR(29) TFR(16) TFR(24)
  x0 += ks2; x1 += k0 + 2u;
  TFR(13) TFR(15) TFR(26) TFR(6)
  x0 += k0; x1 += k1 + 3u;
  TFR(17) TFR(29) TFR(16) TFR(24)
  x0 += k1; x1 += ks2 + 4u;
  TFR(13) TFR(15) TFR(26) TFR(6)
  x0 += ks2; x1 += k0 + 5u;
#undef TFR
  o0 = x0; o1 = x1;
}

// ---------------- k0: zero counts/selu/base ----------------
__global__ void k_zero(unsigned* __restrict__ p, int n) {
  int i = blockIdx.x * blockDim.x + threadIdx.x;
  if (i < n) p[i] = 0u;
}

// ---------------- k1: sample key indices, histogram counts ----------------
// counts[h][b][j] = multiplicity of key j in the 7097 draws for (head h, batch b)
__global__ void k_sample(unsigned* __restrict__ counts) {
  __shared__ uint32_t sk[2];  // k2 of randint's internal split, per head
  int h = blockIdx.y;
  if (threadIdx.x == 0) {
    uint32_t hk0, hk1, t0, t1;
#if THREEFRY_PARTITIONABLE
    threefry2x32(0u, 42u, 0u, (uint32_t)h, hk0, hk1);   // head_keys = split (foldlike)
    threefry2x32(hk0, hk1, 0u, 1u, t0, t1);             // k2 = split(head_key)[1]
    sk[0] = t0; sk[1] = t1;
#else
    uint32_t a0, a1, b0, b1, c0, c1;
    int i0 = 2 * h, i1 = 2 * h + 1;  // original split: flat[i] = i<16 ? o0(i,i+16) : o1(i-16,i)
    if (i0 < 16) { threefry2x32(0u, 42u, (uint32_t)i0, (uint32_t)(i0 + 16), a0, a1); hk0 = a0; }
    else         { threefry2x32(0u, 42u, (uint32_t)(i0 - 16), (uint32_t)i0, a0, a1); hk0 = a1; }
    if (i1 < 16) { threefry2x32(0u, 42u, (uint32_t)i1, (uint32_t)(i1 + 16), a0, a1); hk1 = a0; }
    else         { threefry2x32(0u, 42u, (uint32_t)(i1 - 16), (uint32_t)i1, a0, a1); hk1 = a1; }
    threefry2x32(hk0, hk1, 0u, 2u, b0, b1);  // split(head_key): k2=(o1(0,2), o1(1,3))
    threefry2x32(hk0, hk1, 1u, 3u, c0, c1);
    sk[0] = b1; sk[1] = c1;
#endif
  }
  __syncthreads();
  int j = blockIdx.x * blockDim.x + threadIdx.x;
  if (j >= USAMP) return;
  for (int b = 0; b < BB; b++) {
    uint32_t o0, o1, bits;
#if THREEFRY_PARTITIONABLE
    threefry2x32(sk[0], sk[1], 0u, (uint32_t)(b * USAMP + j), o0, o1);
    bits = o0 ^ o1;                         // partitionable random_bits (32-bit)
#else
    threefry2x32(sk[0], sk[1], (uint32_t)j, (uint32_t)(j + USAMP), o0, o1);
    bits = (b == 0) ? o0 : o1;              // original: out = concat(o0[], o1[])
#endif
    // randint span=1024 divides 2^16 -> multiplier term = 0 -> idx = bits % 1024
    atomicAdd(&counts[((size_t)h * BB + b) * LK + (bits & (LK - 1))], 1u);
  }
}

// ---------------- k2: kmean (count-weighted) + vmean ----------------
__global__ void k_means(const float* __restrict__ kk, const float* __restrict__ v,
                        const unsigned* __restrict__ counts,
                        float* __restrict__ kmean, float* __restrict__ vmean) {
  int bid = blockIdx.x, d = threadIdx.x;  // 64 threads
  if (bid < NH * BB) {
    int b = bid % BB;
    const unsigned* cnt = counts + (size_t)bid * LK;
    const float* kb = kk + (size_t)b * LK * DH;
    float acc = 0.f;
    for (int j = 0; j < LK; j++) acc += (float)cnt[j] * kb[(size_t)j * DH + d];
    kmean[(size_t)bid * DH + d] = acc / (float)USAMP;  // sampled-mean key vector
  } else {
    int b = bid - NH * BB;
    const float* vb = v + (size_t)b * LK * DH;
    float acc = 0.f;
    for (int j = 0; j < LK; j++) acc += vb[(size_t)j * DH + d];
    vmean[b * DH + d] = acc * (1.0f / LK);
  }
}

// ---------------- k3: S[b,i,j] = q_i . k_j  (shared across heads) ----------------
__global__ __launch_bounds__(256) void k_scores(const float* __restrict__ q,
                                                const float* __restrict__ k,
                                                float* __restrict__ S) {
  __shared__ float Qs[64][DH + 1];  // +1 pad: 2-way LDS aliasing only (free)
  __shared__ float Ks[64][DH + 1];
  int b = blockIdx.z;
  int i0 = blockIdx.y * 64, j0 = blockIdx.x * 64;
  int t = threadIdx.x;
  const float* qb = q + ((size_t)b * LQ + i0) * DH;
  const float* kb = k + ((size_t)b * LK + j0) * DH;
#pragma unroll
  for (int rep = 0; rep < 4; rep++) {
    int lin = (rep * 256 + t) * 4;
    int r = lin >> 6, c = lin & 63;
    float4 qv = *(const float4*)(qb + (size_t)r * DH + c);
    float4 kv = *(const float4*)(kb + (size_t)r * DH + c);
    Qs[r][c] = qv.x; Qs[r][c + 1] = qv.y; Qs[r][c + 2] = qv.z; Qs[r][c + 3] = qv.w;
    Ks[r][c] = kv.x; Ks[r][c + 1] = kv.y; Ks[r][c + 2] = kv.z; Ks[r][c + 3] = kv.w;
  }
  __syncthreads();
  int tx = t & 15, ty = t >> 4;
  float acc[4][4] = {};
  for (int d = 0; d < DH; d++) {
    float a[4], bb[4];
#pragma unroll
    for (int r = 0; r < 4; r++) a[r] = Qs[ty * 4 + r][d];
#pragma unroll
    for (int c = 0; c < 4; c++) bb[c] = Ks[tx * 4 + c][d];
#pragma unroll
    for (int r = 0; r < 4; r++)
#pragma unroll
      for (int c = 0; c < 4; c++) acc[r][c] += a[r] * bb[c];
  }
  float* Sb = S + ((size_t)b * LQ + i0) * LK + j0;
#pragma unroll
  for (int r = 0; r < 4; r++) {
    *(float4*)(Sb + (size_t)(ty * 4 + r) * LK + tx * 4) =
        make_float4(acc[r][0], acc[r][1], acc[r][2], acc[r][3]);
  }
}

// ------- k4: M[h,b,i] = max_{sampled j} S[i,j] - q_i.kmean[h,b] — all heads in one S pass
__global__ __launch_bounds__(256) void k_M(const float* __restrict__ q,
                                           const float* __restrict__ S,
                                           const unsigned* __restrict__ counts,
                                           const float* __restrict__ kmean,
                                           float* __restrict__ M) {
  int b = blockIdx.y;
  __shared__ uint32_t mask[NH][LK / 32];  // 2 KB: per-head sampled-key bitmask
  int t = threadIdx.x;
  for (int w = t; w < NH * (LK / 32); w += 256) {
    int h = w >> 5, blk = w & 31;
    const unsigned* cnt = counts + ((size_t)h * BB + b) * LK + blk * 32;
    uint32_t m = 0;
    for (int z = 0; z < 32; z++) m |= (cnt[z] != 0u ? 1u : 0u) << z;
    mask[h][blk] = m;
  }
  __syncthreads();
  int lane = t & 63, w4 = t >> 6;       // 4 waves = 4 query rows per block
  int i = blockIdx.x * 4 + w4;
  const float* Srow = S + ((size_t)b * LQ + i) * LK;
  float mx[NH];
#pragma unroll
  for (int h = 0; h < NH; h++) mx[h] = -INFINITY;
  for (int j = lane; j < LK; j += 64) {
    float s = Srow[j];  // loaded ONCE, tested against all 16 head masks
#pragma unroll
    for (int h = 0; h < NH; h++) {
      bool on = (mask[h][j >> 5] >> (j & 31)) & 1u;
      mx[h] = fmaxf(mx[h], on ? s : -INFINITY);
    }
  }
#pragma unroll
  for (int h = 0; h < NH; h++) {
#pragma unroll
    for (int off = 32; off > 0; off >>= 1) mx[h] = fmaxf(mx[h], __shfl_xor(mx[h], off));
  }
  float qv = q[((size_t)b * LQ + i) * DH + lane];  // lane == d (DH==64)
#pragma unroll
  for (int h = 0; h < NH; h++) {
    float p = qv * kmean[((size_t)h * BB + b) * DH + lane];
#pragma unroll
    for (int off = 32; off > 0; off >>= 1) p += __shfl_xor(p, off);
    mx[h] -= p;
  }
  if (lane == 0) {
#pragma unroll
    for (int h = 0; h < NH; h++) M[((size_t)h * BB + b) * LQ + i] = mx[h];
  }
}

// ---------------- k5: top-34 of M per (h,b); fill topidx + selu table ----------------
__global__ __launch_bounds__(256) void k_topk(const float* __restrict__ M,
                                              int* __restrict__ topidx,
                                              int* __restrict__ selu) {
  int hb = blockIdx.x;
  __shared__ float vals[LQ];
  __shared__ float rv[256];
  __shared__ int   ri[256];
  int t = threadIdx.x;
  for (int i = t; i < LQ; i += 256) vals[i] = M[(size_t)hb * LQ + i];
  __syncthreads();
  for (int u = 0; u < USEL; u++) {
    float bv = -INFINITY; int bi = 0;
    for (int i = t; i < LQ; i += 256) {       // ascending scan + strict '>' => lowest idx on tie
      float x = vals[i];
      if (x > bv) { bv = x; bi = i; }
    }
    rv[t] = bv; ri[t] = bi;
    __syncthreads();
    for (int s = 128; s > 0; s >>= 1) {
      if (t < s) {
        if (rv[t + s] > rv[t] || (rv[t + s] == rv[t] && ri[t + s] < ri[t])) {
          rv[t] = rv[t + s]; ri[t] = ri[t + s];
        }
      }
      __syncthreads();
    }
    if (t == 0) {
      int sel = ri[0];
      topidx[hb * USEL + u] = sel;
      selu[(size_t)hb * LQ + sel] = u + 1;    // 0 = not selected
      vals[sel] = -INFINITY;
    }
    __syncthreads();
  }
}

// ---------------- k6: softmax(S_row/32) @ v for selected rows; delta = s1 - vmean ----
__global__ __launch_bounds__(256) void k_attn(const float* __restrict__ S,
                                              const float* __restrict__ v,
                                              const int* __restrict__ topidx,
                                              const float* __restrict__ vmean,
                                              float* __restrict__ delta) {
  int hb = blockIdx.y, u = blockIdx.x;
  int b = hb % BB;
  int t = threadIdx.x;
  __shared__ float p[LK];
  __shared__ float red[256];
  __shared__ float part[4][DH];
  __shared__ float smx, ssum;
  int i = topidx[hb * USEL + u];
  const float* Srow = S + ((size_t)b * LQ + i) * LK;
  float lmx = -INFINITY;
  for (int j = t; j < LK; j += 256) {
    float x = Srow[j] * 0.03125f;   // 1/sqrt(1024) = 1/32 exactly
    p[j] = x;
    lmx = fmaxf(lmx, x);
  }
  red[t] = lmx; __syncthreads();
  for (int s = 128; s > 0; s >>= 1) { if (t < s) red[t] = fmaxf(red[t], red[t + s]); __syncthreads(); }
  if (t == 0) smx = red[0];
  __syncthreads();
  float mx = smx;
  float lsum = 0.f;
  for (int j = t; j < LK; j += 256) { float e = expf(p[j] - mx); p[j] = e; lsum += e; }
  red[t] = lsum; __syncthreads();
  for (int s = 128; s > 0; s >>= 1) { if (t < s) red[t] += red[t + s]; __syncthreads(); }
  if (t == 0) ssum = red[0];
  __syncthreads();
  float inv = 1.0f / ssum;          // fold normalization into the PV epilogue
  int d = t & 63, g = t >> 6;
  const float* vb = v + (size_t)b * LK * DH;
  float acc = 0.f;
  for (int j = g; j < LK; j += 4) acc += p[j] * vb[(size_t)j * DH + d];
  part[g][d] = acc;
  __syncthreads();
  if (t < DH) {
    float s1 = (part[0][t] + part[1][t] + part[2][t] + part[3][t]) * inv;
    delta[((size_t)hb * USEL + u) * DH + t] = s1 - vmean[b * DH + t];
  }
}

// ---------------- k7: base[b,o] = sum_j tile(vmean)[j] * W[j,o] (atomic partials) ----
__global__ __launch_bounds__(256) void k_base(const float* __restrict__ W,
                                              const float* __restrict__ vmean,
                                              float* __restrict__ base) {
  __shared__ float vm[DH];
  int b = blockIdx.y, hc = blockIdx.z;
  int o = blockIdx.x * 256 + threadIdx.x;
  if (threadIdx.x < DH) vm[threadIdx.x] = vmean[b * DH + threadIdx.x];
  __syncthreads();
  const float* Wr = W + (size_t)hc * DH * DM + o;
  float acc = 0.f;
#pragma unroll
  for (int d = 0; d < DH; d++) acc += vm[d] * Wr[(size_t)d * DM];
  atomicAdd(&base[b * DM + o], acc);
}

// ---------------- k8: Y[b,i,:] = base + b_proj + sum_{selected h} delta @ W_h ------
__global__ __launch_bounds__(256) void k_out(const float* __restrict__ W,
                                             const float* __restrict__ bproj,
                                             const float* __restrict__ base,
                                             const int* __restrict__ selu,
                                             const float* __restrict__ delta,
                                             float* __restrict__ out) {
  int bi = blockIdx.x;               // b*LQ + i
  int b = bi / LQ, i = bi % LQ;
  int t = threadIdx.x;
  __shared__ float dl[DH];
  float acc[4];
#pragma unroll
  for (int rep = 0; rep < 4; rep++) {
    int o = rep * 256 + t;
    acc[rep] = base[b * DM + o] + bproj[o];
  }
  for (int h = 0; h < NH; h++) {
    int u = selu[((size_t)h * BB + b) * LQ + i];  // block-uniform -> uniform branch
    if (u == 0) continue;
    __syncthreads();
    if (t < DH) dl[t] = delta[(((size_t)h * BB + b) * USEL + (u - 1)) * DH + t];
    __syncthreads();
    const float* Wh = W + (size_t)h * DH * DM;
#pragma unroll
    for (int rep = 0; rep < 4; rep++) {
      int o = rep * 256 + t;
      float a = acc[rep];
#pragma unroll
      for (int d = 0; d < DH; d++) a += dl[d] * Wh[(size_t)d * DM + o];
      acc[rep] = a;
    }
  }
#pragma unroll
  for (int rep = 0; rep < 4; rep++) {
    int o = rep * 256 + t;
    out[(size_t)bi * DM + o] = acc[rep];
  }
}

// ---------------- host ----------------
extern "C" void kernel_launch(void* const* d_in, const int* in_sizes, int n_in,
                              void* d_out, int out_size, void* d_ws, size_t ws_size,
                              hipStream_t stream) {
  const float* q  = (const float*)d_in[0];
  const float* k  = (const float*)d_in[1];
  const float* v  = (const float*)d_in[2];
  const float* W  = (const float*)d_in[3];
  const float* bp = (const float*)d_in[4];
  float* out = (float*)d_out;

  // S lives in d_out: BB*LQ*LK == out_size == 2M floats (8 MB). All S consumers
  // (k_M, k_attn) run before k_out overwrites d_out. Stream-serialized => safe.
  float* S = out;

  // workspace layout (zeroed region first: counts, selu, base) — ~677 KB total
  char* w = (char*)d_ws;
  unsigned* counts = (unsigned*)w;            w += (size_t)NH * BB * LK * 4;        // 128 KB
  int*      selu   = (int*)w;                 w += (size_t)NH * BB * LQ * 4;        // 128 KB
  float*    base   = (float*)w;               w += (size_t)BB * DM * 4;             // 8 KB
  float*    kmean  = (float*)w;               w += (size_t)NH * BB * DH * 4;        // 8 KB
  float*    vmean  = (float*)w;               w += (size_t)BB * DH * 4;             // 512 B
  float*    M      = (float*)w;               w += (size_t)NH * BB * LQ * 4;        // 128 KB
  int*      topidx = (int*)w;                 w += (size_t)NH * BB * USEL * 4;      // 4.25 KB
  float*    delta  = (float*)w;               w += (size_t)NH * BB * USEL * DH * 4; // 272 KB
  if ((size_t)(w - (char*)d_ws) > ws_size) return;  // refuse to scribble OOB

  const int ZW = NH * BB * LK + NH * BB * LQ + BB * DM;  // u32 words to zero
  k_zero  <<<(ZW + 255) / 256, 256, 0, stream>>>(counts, ZW);
  k_sample<<<dim3((USAMP + 255) / 256, NH), 256, 0, stream>>>(counts);
  k_means <<<NH * BB + BB, 64, 0, stream>>>(k, v, counts, kmean, vmean);
  k_scores<<<dim3(LK / 64, LQ / 64, BB), 256, 0, stream>>>(q, k, S);
  k_M     <<<dim3(LQ / 4, BB), 256, 0, stream>>>(q, S, counts, kmean, M);
  k_topk  <<<NH * BB, 256, 0, stream>>>(M, topidx, selu);
  k_attn  <<<dim3(USEL, NH * BB), 256, 0, stream>>>(S, v, topidx, vmean, delta);
  k_base  <<<dim3(DM / 256, BB, NH), 256, 0, stream>>>(W, vmean, base);
  k_out   <<<BB * LQ, 256, 0, stream>>>(W, bp, base, selu, delta, out);
}

// Round 3
// 285.110 us; speedup vs baseline: 1.1445x; 1.1445x over previous
//
#include <hip/hip_runtime.h>
#include <math.h>
#include <stdint.h>
#include <stddef.h>

// ProbSparse multi-head attention (Informer-style), fp32, MI355X.
// Heads share q,k,v; only the threefry-sampled key set differs per head.
// S (the shared 2x1024x1024 score matrix) lives in d_out and is consumed
// (k_M, k_attn) before k_fill/k_corr overwrite d_out with the final result.

#define BB     2
#define LQ     1024
#define LK     1024
#define DH     64
#define NH     16
#define DM     1024
#define USEL   34
#define USAMP  7097

#define THREEFRY_PARTITIONABLE 1

// ---------------- threefry2x32 (matches jax._src.prng) ----------------
__device__ __forceinline__ uint32_t rotl32(uint32_t x, int d) {
  return (x << d) | (x >> (32 - d));
}

__device__ __forceinline__ void threefry2x32(uint32_t k0, uint32_t k1,
                                             uint32_t x0, uint32_t x1,
                                             uint32_t& o0, uint32_t& o1) {
  uint32_t ks2 = k0 ^ k1 ^ 0x1BD11BDAu;
  x0 += k0; x1 += k1;
#define TFR(r) { x0 += x1; x1 = rotl32(x1, (r)); x1 ^= x0; }
  TFR(13) TFR(15) TFR(26) TFR(6)
  x0 += k1; x1 += ks2 + 1u;
  TFR(17) TFR(29) TFR(16) TFR(24)
  x0 += ks2; x1 += k0 + 2u;
  TFR(13) TFR(15) TFR(26) TFR(6)
  x0 += k0; x1 += k1 + 3u;
  TFR(17) TFR(29) TFR(16) TFR(24)
  x0 += k1; x1 += ks2 + 4u;
  TFR(13) TFR(15) TFR(26) TFR(6)
  x0 += ks2; x1 += k0 + 5u;
#undef TFR
  o0 = x0; o1 = x1;
}

// ---------------- k0: zero counts/selu/base ----------------
__global__ void k_zero(unsigned* __restrict__ p, int n) {
  int i = blockIdx.x * blockDim.x + threadIdx.x;
  if (i < n) p[i] = 0u;
}

// ---------------- k1: sample key indices, histogram counts ----------------
__global__ void k_sample(unsigned* __restrict__ counts) {
  __shared__ uint32_t sk[2];
  int h = blockIdx.y;
  if (threadIdx.x == 0) {
    uint32_t hk0, hk1, t0, t1;
#if THREEFRY_PARTITIONABLE
    threefry2x32(0u, 42u, 0u, (uint32_t)h, hk0, hk1);   // head_keys = split (foldlike)
    threefry2x32(hk0, hk1, 0u, 1u, t0, t1);             // k2 = split(head_key)[1]
    sk[0] = t0; sk[1] = t1;
#else
    uint32_t a0, a1, b0, b1, c0, c1;
    int i0 = 2 * h, i1 = 2 * h + 1;
    if (i0 < 16) { threefry2x32(0u, 42u, (uint32_t)i0, (uint32_t)(i0 + 16), a0, a1); hk0 = a0; }
    else         { threefry2x32(0u, 42u, (uint32_t)(i0 - 16), (uint32_t)i0, a0, a1); hk0 = a1; }
    if (i1 < 16) { threefry2x32(0u, 42u, (uint32_t)i1, (uint32_t)(i1 + 16), a0, a1); hk1 = a0; }
    else         { threefry2x32(0u, 42u, (uint32_t)(i1 - 16), (uint32_t)i1, a0, a1); hk1 = a1; }
    threefry2x32(hk0, hk1, 0u, 2u, b0, b1);
    threefry2x32(hk0, hk1, 1u, 3u, c0, c1);
    sk[0] = b1; sk[1] = c1;
#endif
  }
  __syncthreads();
  int j = blockIdx.x * blockDim.x + threadIdx.x;
  if (j >= USAMP) return;
  for (int b = 0; b < BB; b++) {
    uint32_t o0, o1, bits;
#if THREEFRY_PARTITIONABLE
    threefry2x32(sk[0], sk[1], 0u, (uint32_t)(b * USAMP + j), o0, o1);
    bits = o0 ^ o1;
#else
    threefry2x32(sk[0], sk[1], (uint32_t)j, (uint32_t)(j + USAMP), o0, o1);
    bits = (b == 0) ? o0 : o1;
#endif
    // randint span=1024 divides 2^16 -> multiplier term = 0 -> idx = bits % 1024
    atomicAdd(&counts[((size_t)h * BB + b) * LK + (bits & (LK - 1))], 1u);
  }
}

// ---------------- k2: kmean (count-weighted) + vmean, 256 thr ----------------
__global__ __launch_bounds__(256) void k_means(const float* __restrict__ kk,
                                               const float* __restrict__ v,
                                               const unsigned* __restrict__ counts,
                                               float* __restrict__ kmean,
                                               float* __restrict__ vmean) {
  int bid = blockIdx.x, t = threadIdx.x, d = t & 63, g = t >> 6;
  __shared__ float part[4][DH];
  if (bid < NH * BB) {
    int b = bid & 1;
    const unsigned* cnt = counts + (size_t)bid * LK;
    const float* kb = kk + (size_t)b * LK * DH;
    float acc = 0.f;
    for (int j = g; j < LK; j += 4) acc += (float)cnt[j] * kb[(size_t)j * DH + d];
    part[g][d] = acc;
    __syncthreads();
    if (t < DH)
      kmean[(size_t)bid * DH + t] =
          (part[0][t] + part[1][t] + part[2][t] + part[3][t]) / (float)USAMP;
  } else {
    int b = bid - NH * BB;
    const float* vb = v + (size_t)b * LK * DH;
    float acc = 0.f;
    for (int j = g; j < LK; j += 4) acc += vb[(size_t)j * DH + d];
    part[g][d] = acc;
    __syncthreads();
    if (t < DH)
      vmean[b * DH + t] =
          (part[0][t] + part[1][t] + part[2][t] + part[3][t]) * (1.0f / LK);
  }
}

// ------- k3: S[b,i,j] = q_i . k_j — transposed LDS, outer-product inner loop
__global__ __launch_bounds__(256) void k_scores(const float* __restrict__ q,
                                                const float* __restrict__ k,
                                                float* __restrict__ S) {
  __shared__ float Qt[DH][68];  // [d][row]; stride 68 words = 272B (16B-aligned,
  __shared__ float Kt[DH][68];  //  b128 row-reads land 2-way max = free)
  int b = blockIdx.z;
  int i0 = blockIdx.y * 64, j0 = blockIdx.x * 64;
  int t = threadIdx.x;
  const float* qb = q + ((size_t)b * LQ + i0) * DH;
  const float* kb = k + ((size_t)b * LK + j0) * DH;
#pragma unroll
  for (int rep = 0; rep < 4; rep++) {
    int lin = (rep * 256 + t) * 4;
    int r = lin >> 6, c = lin & 63;
    float4 qv = *(const float4*)(qb + (size_t)r * DH + c);
    float4 kv = *(const float4*)(kb + (size_t)r * DH + c);
    Qt[c][r] = qv.x; Qt[c + 1][r] = qv.y; Qt[c + 2][r] = qv.z; Qt[c + 3][r] = qv.w;
    Kt[c][r] = kv.x; Kt[c + 1][r] = kv.y; Kt[c + 2][r] = kv.z; Kt[c + 3][r] = kv.w;
  }
  __syncthreads();
  int tx = t & 15, ty = t >> 4;
  float acc[4][4] = {};
#pragma unroll 8
  for (int d = 0; d < DH; d++) {
    float4 av = *(const float4*)&Qt[d][ty * 4];   // 4 q-rows at this d
    float4 bv = *(const float4*)&Kt[d][tx * 4];   // 4 k-rows at this d
    acc[0][0] += av.x * bv.x; acc[0][1] += av.x * bv.y; acc[0][2] += av.x * bv.z; acc[0][3] += av.x * bv.w;
    acc[1][0] += av.y * bv.x; acc[1][1] += av.y * bv.y; acc[1][2] += av.y * bv.z; acc[1][3] += av.y * bv.w;
    acc[2][0] += av.z * bv.x; acc[2][1] += av.z * bv.y; acc[2][2] += av.z * bv.z; acc[2][3] += av.z * bv.w;
    acc[3][0] += av.w * bv.x; acc[3][1] += av.w * bv.y; acc[3][2] += av.w * bv.z; acc[3][3] += av.w * bv.w;
  }
  float* Sb = S + ((size_t)b * LQ + i0) * LK + j0;
#pragma unroll
  for (int r = 0; r < 4; r++) {
    *(float4*)(Sb + (size_t)(ty * 4 + r) * LK + tx * 4) =
        make_float4(acc[r][0], acc[r][1], acc[r][2], acc[r][3]);
  }
}

// ------- k4: M[h,b,i] = max_{sampled j} S[i,j] - q_i.kmean[h,b] — all heads, one S pass
__global__ __launch_bounds__(256) void k_M(const float* __restrict__ q,
                                           const float* __restrict__ S,
                                           const unsigned* __restrict__ counts,
                                           const float* __restrict__ kmean,
                                           float* __restrict__ M) {
  int b = blockIdx.y;
  __shared__ uint32_t mask[NH][LK / 32];  // 2 KB per-head sampled-key bitmask
  int t = threadIdx.x;
  for (int w = t; w < NH * (LK / 32); w += 256) {
    int h = w >> 5, blk = w & 31;
    const unsigned* cnt = counts + ((size_t)h * BB + b) * LK + blk * 32;
    uint32_t m = 0;
    for (int z = 0; z < 32; z++) m |= (cnt[z] != 0u ? 1u : 0u) << z;
    mask[h][blk] = m;
  }
  __syncthreads();
  int lane = t & 63, w4 = t >> 6;
  int i = blockIdx.x * 4 + w4;
  const float* Srow = S + ((size_t)b * LQ + i) * LK;
  float mx[NH];
#pragma unroll
  for (int h = 0; h < NH; h++) mx[h] = -INFINITY;
  for (int j = lane; j < LK; j += 64) {
    float s = Srow[j];
#pragma unroll
    for (int h = 0; h < NH; h++) {
      bool on = (mask[h][j >> 5] >> (j & 31)) & 1u;
      mx[h] = fmaxf(mx[h], on ? s : -INFINITY);
    }
  }
#pragma unroll
  for (int h = 0; h < NH; h++) {
#pragma unroll
    for (int off = 32; off > 0; off >>= 1) mx[h] = fmaxf(mx[h], __shfl_xor(mx[h], off));
  }
  float qv = q[((size_t)b * LQ + i) * DH + lane];  // lane == d (DH==64)
#pragma unroll
  for (int h = 0; h < NH; h++) {
    float p = qv * kmean[((size_t)h * BB + b) * DH + lane];
#pragma unroll
    for (int off = 32; off > 0; off >>= 1) p += __shfl_xor(p, off);
    mx[h] -= p;
  }
  if (lane == 0) {
#pragma unroll
    for (int h = 0; h < NH; h++) M[((size_t)h * BB + b) * LQ + i] = mx[h];
  }
}

// ---------------- k5: top-34 per (h,b) — shfl-based argmax, 2 barriers/iter ----
__global__ __launch_bounds__(256) void k_topk(const float* __restrict__ M,
                                              int* __restrict__ topidx,
                                              int* __restrict__ selu) {
  int hb = blockIdx.x, t = threadIdx.x;
  __shared__ float vals[LQ];
  __shared__ float wv[4];
  __shared__ int   wi[4];
  for (int i = t; i < LQ; i += 256) vals[i] = M[(size_t)hb * LQ + i];
  __syncthreads();
  int lane = t & 63, w = t >> 6;
  for (int u = 0; u < USEL; u++) {
    float bv = -INFINITY; int bi = 0x7fffffff;
#pragma unroll
    for (int r = 0; r < 4; r++) {     // ascending idx + strict '>' => lowest idx on tie
      int i = r * 256 + t;
      float x = vals[i];
      if (x > bv) { bv = x; bi = i; }
    }
#pragma unroll
    for (int off = 32; off > 0; off >>= 1) {
      float ov = __shfl_xor(bv, off);
      int   oi = __shfl_xor(bi, off);
      if (ov > bv || (ov == bv && oi < bi)) { bv = ov; bi = oi; }
    }
    if (lane == 0) { wv[w] = bv; wi[w] = bi; }
    __syncthreads();
    if (t == 0) {
      float fv = wv[0]; int fi = wi[0];
#pragma unroll
      for (int x = 1; x < 4; x++)
        if (wv[x] > fv || (wv[x] == fv && wi[x] < fi)) { fv = wv[x]; fi = wi[x]; }
      topidx[hb * USEL + u] = fi;
      selu[(size_t)hb * LQ + fi] = u + 1;   // 0 = not selected
      vals[fi] = -INFINITY;
    }
    __syncthreads();
  }
}

// ------- k6: softmax(S_row/32) @ v for selected rows; delta = s1 - vmean ------
__global__ __launch_bounds__(256) void k_attn(const float* __restrict__ S,
                                              const float* __restrict__ v,
                                              const int* __restrict__ topidx,
                                              const float* __restrict__ vmean,
                                              float* __restrict__ delta) {
  int hb = blockIdx.y, u = blockIdx.x;
  int b = hb % BB;
  int t = threadIdx.x, lane = t & 63, w = t >> 6;
  __shared__ float p[LK];
  __shared__ float wred[4];
  __shared__ float wred2[4];
  __shared__ float part[4][DH];
  int i = topidx[hb * USEL + u];
  const float* Srow = S + ((size_t)b * LQ + i) * LK;
  float lmx = -INFINITY;
#pragma unroll
  for (int r = 0; r < 4; r++) {
    int j = r * 256 + t;
    float x = Srow[j] * 0.03125f;   // 1/sqrt(1024) = 1/32 exactly
    p[j] = x;
    lmx = fmaxf(lmx, x);
  }
#pragma unroll
  for (int off = 32; off > 0; off >>= 1) lmx = fmaxf(lmx, __shfl_xor(lmx, off));
  if (lane == 0) wred[w] = lmx;
  __syncthreads();
  float mx = fmaxf(fmaxf(wred[0], wred[1]), fmaxf(wred[2], wred[3]));
  float lsum = 0.f;
#pragma unroll
  for (int r = 0; r < 4; r++) {
    int j = r * 256 + t;
    float e = expf(p[j] - mx);
    p[j] = e;
    lsum += e;
  }
#pragma unroll
  for (int off = 32; off > 0; off >>= 1) lsum += __shfl_xor(lsum, off);
  if (lane == 0) wred2[w] = lsum;
  __syncthreads();                  // p[] final + wred2 visible
  int d = lane, g = w;
  const float* vb = v + (size_t)b * LK * DH;
  float acc = 0.f;
  for (int j = g; j < LK; j += 4) acc += p[j] * vb[(size_t)j * DH + d];
  part[g][d] = acc;
  __syncthreads();
  if (t < DH) {
    float inv = 1.0f / (wred2[0] + wred2[1] + wred2[2] + wred2[3]);
    float s1 = (part[0][t] + part[1][t] + part[2][t] + part[3][t]) * inv;
    delta[((size_t)hb * USEL + u) * DH + t] = s1 - vmean[b * DH + t];
  }
}

// ---------------- k7: base[b,o] = sum_j tile(vmean)[j] * W[j,o] ----------------
__global__ __launch_bounds__(256) void k_base(const float* __restrict__ W,
                                              const float* __restrict__ vmean,
                                              float* __restrict__ base) {
  __shared__ float vm[DH];
  int b = blockIdx.y, hc = blockIdx.z;
  int o = blockIdx.x * 256 + threadIdx.x;
  if (threadIdx.x < DH) vm[threadIdx.x] = vmean[b * DH + threadIdx.x];
  __syncthreads();
  const float* Wr = W + (size_t)hc * DH * DM + o;
  float acc = 0.f;
#pragma unroll
  for (int d = 0; d < DH; d++) acc += vm[d] * Wr[(size_t)d * DM];
  atomicAdd(&base[b * DM + o], acc);
}

// ---------------- k8a: out[b,i,:] = base[b,:] + bproj  (dense fill) ----------------
__global__ __launch_bounds__(256) void k_fill(const float* __restrict__ base,
                                              const float* __restrict__ bproj,
                                              float* __restrict__ out) {
  int idx = blockIdx.x * 256 + threadIdx.x;        // float4 index
  int o4 = idx & (DM / 4 - 1);
  int b = idx >> 18;                               // idx / (LQ*DM/4)
  float4 bs = ((const float4*)base)[b * (DM / 4) + o4];
  float4 bp = ((const float4*)bproj)[o4];
  ((float4*)out)[idx] = make_float4(bs.x + bp.x, bs.y + bp.y, bs.z + bp.z, bs.w + bp.w);
}

// ------- k8b: one block per selected (h,b,u): out[b,i,:] += delta @ W_h ------
__global__ __launch_bounds__(256) void k_corr(const float* __restrict__ W,
                                              const int* __restrict__ topidx,
                                              const float* __restrict__ delta,
                                              float* __restrict__ out) {
  int u = blockIdx.x, hb = blockIdx.y;             // hb = h*BB + b
  int h = hb >> 1, b = hb & 1;
  int t = threadIdx.x;
  __shared__ float dl[DH];
  int i = topidx[hb * USEL + u];
  if (t < DH) dl[t] = delta[((size_t)hb * USEL + u) * DH + t];
  __syncthreads();
  const float* Wh = W + (size_t)h * DH * DM;
  float* orow = out + ((size_t)b * LQ + i) * DM;
#pragma unroll
  for (int rep = 0; rep < 4; rep++) {
    int o = rep * 256 + t;
    float acc = 0.f;
#pragma unroll 16
    for (int d = 0; d < DH; d++) acc += dl[d] * Wh[(size_t)d * DM + o];
    atomicAdd(&orow[o], acc);                       // heads may share a row
  }
}

// ---------------- host ----------------
extern "C" void kernel_launch(void* const* d_in, const int* in_sizes, int n_in,
                              void* d_out, int out_size, void* d_ws, size_t ws_size,
                              hipStream_t stream) {
  const float* q  = (const float*)d_in[0];
  const float* k  = (const float*)d_in[1];
  const float* v  = (const float*)d_in[2];
  const float* W  = (const float*)d_in[3];
  const float* bp = (const float*)d_in[4];
  float* out = (float*)d_out;

  // S lives in d_out (8 MB): consumed by k_M/k_attn before k_fill overwrites it.
  float* S = out;

  char* w = (char*)d_ws;
  unsigned* counts = (unsigned*)w;            w += (size_t)NH * BB * LK * 4;        // 128 KB
  int*      selu   = (int*)w;                 w += (size_t)NH * BB * LQ * 4;        // 128 KB
  float*    base   = (float*)w;               w += (size_t)BB * DM * 4;             // 8 KB
  float*    kmean  = (float*)w;               w += (size_t)NH * BB * DH * 4;        // 8 KB
  float*    vmean  = (float*)w;               w += (size_t)BB * DH * 4;             // 512 B
  float*    M      = (float*)w;               w += (size_t)NH * BB * LQ * 4;        // 128 KB
  int*      topidx = (int*)w;                 w += (size_t)NH * BB * USEL * 4;      // 4.25 KB
  float*    delta  = (float*)w;               w += (size_t)NH * BB * USEL * DH * 4; // 272 KB
  if ((size_t)(w - (char*)d_ws) > ws_size) return;

  const int ZW = NH * BB * LK + NH * BB * LQ + BB * DM;
  k_zero  <<<(ZW + 255) / 256, 256, 0, stream>>>(counts, ZW);
  k_sample<<<dim3((USAMP + 255) / 256, NH), 256, 0, stream>>>(counts);
  k_means <<<NH * BB + BB, 256, 0, stream>>>(k, v, counts, kmean, vmean);
  k_scores<<<dim3(LK / 64, LQ / 64, BB), 256, 0, stream>>>(q, k, S);
  k_M     <<<dim3(LQ / 4, BB), 256, 0, stream>>>(q, S, counts, kmean, M);
  k_topk  <<<NH * BB, 256, 0, stream>>>(M, topidx, selu);
  k_attn  <<<dim3(USEL, NH * BB), 256, 0, stream>>>(S, v, topidx, vmean, delta);
  k_base  <<<dim3(DM / 256, BB, NH), 256, 0, stream>>>(W, vmean, base);
  k_fill  <<<(BB * LQ * DM / 4) / 256, 256, 0, stream>>>(base, bp, out);
  k_corr  <<<dim3(USEL, NH * BB), 256, 0, stream>>>(W, topidx, delta, out);
}

// Round 6
// 219.699 us; speedup vs baseline: 1.4852x; 1.2977x over previous
//
#include <hip/hip_runtime.h>
#include <math.h>
#include <stdint.h>
#include <stddef.h>

// ProbSparse multi-head attention (Informer-style), fp32, MI355X.
// Heads share q,k,v; only the threefry-sampled key set differs per head.
// S (the shared 2x1024x1024 score matrix) lives in d_out and is consumed
// (k_M, k_attn) before k_fill/k_corr overwrite d_out with the final result.

#define BB     2
#define LQ     1024
#define LK     1024
#define DH     64
#define NH     16
#define DM     1024
#define USEL   34
#define USAMP  7097
#define NSLICE 8   // j-dimension slices in k_means

#define THREEFRY_PARTITIONABLE 1

// ---------------- threefry2x32 (matches jax._src.prng) ----------------
__device__ __forceinline__ uint32_t rotl32(uint32_t x, int d) {
  return (x << d) | (x >> (32 - d));
}

__device__ __forceinline__ void threefry2x32(uint32_t k0, uint32_t k1,
                                             uint32_t x0, uint32_t x1,
                                             uint32_t& o0, uint32_t& o1) {
  uint32_t ks2 = k0 ^ k1 ^ 0x1BD11BDAu;
  x0 += k0; x1 += k1;
#define TFR(r) { x0 += x1; x1 = rotl32(x1, (r)); x1 ^= x0; }
  TFR(13) TFR(15) TFR(26) TFR(6)
  x0 += k1; x1 += ks2 + 1u;
  TFR(17) TFR(29) TFR(16) TFR(24)
  x0 += ks2; x1 += k0 + 2u;
  TFR(13) TFR(15) TFR(26) TFR(6)
  x0 += k0; x1 += k1 + 3u;
  TFR(17) TFR(29) TFR(16) TFR(24)
  x0 += k1; x1 += ks2 + 4u;
  TFR(13) TFR(15) TFR(26) TFR(6)
  x0 += ks2; x1 += k0 + 5u;
#undef TFR
  o0 = x0; o1 = x1;
}

// ---------------- k0: zero counts/base/kmean/vmean ----------------
__global__ void k_zero(unsigned* __restrict__ p, int n) {
  int i = blockIdx.x * blockDim.x + threadIdx.x;
  if (i < n) p[i] = 0u;
}

// ---------------- k1: sample key indices, histogram counts ----------------
__global__ void k_sample(unsigned* __restrict__ counts) {
  __shared__ uint32_t sk[2];
  int h = blockIdx.y;
  if (threadIdx.x == 0) {
    uint32_t hk0, hk1, t0, t1;
#if THREEFRY_PARTITIONABLE
    threefry2x32(0u, 42u, 0u, (uint32_t)h, hk0, hk1);   // head_keys = split (foldlike)
    threefry2x32(hk0, hk1, 0u, 1u, t0, t1);             // k2 = split(head_key)[1]
    sk[0] = t0; sk[1] = t1;
#else
    uint32_t a0, a1, b0, b1, c0, c1;
    int i0 = 2 * h, i1 = 2 * h + 1;
    if (i0 < 16) { threefry2x32(0u, 42u, (uint32_t)i0, (uint32_t)(i0 + 16), a0, a1); hk0 = a0; }
    else         { threefry2x32(0u, 42u, (uint32_t)(i0 - 16), (uint32_t)i0, a0, a1); hk0 = a1; }
    if (i1 < 16) { threefry2x32(0u, 42u, (uint32_t)i1, (uint32_t)(i1 + 16), a0, a1); hk1 = a0; }
    else         { threefry2x32(0u, 42u, (uint32_t)(i1 - 16), (uint32_t)i1, a0, a1); hk1 = a1; }
    threefry2x32(hk0, hk1, 0u, 2u, b0, b1);
    threefry2x32(hk0, hk1, 1u, 3u, c0, c1);
    sk[0] = b1; sk[1] = c1;
#endif
  }
  __syncthreads();
  int j = blockIdx.x * blockDim.x + threadIdx.x;
  if (j >= USAMP) return;
  for (int b = 0; b < BB; b++) {
    uint32_t o0, o1, bits;
#if THREEFRY_PARTITIONABLE
    threefry2x32(sk[0], sk[1], 0u, (uint32_t)(b * USAMP + j), o0, o1);
    bits = o0 ^ o1;
#else
    threefry2x32(sk[0], sk[1], (uint32_t)j, (uint32_t)(j + USAMP), o0, o1);
    bits = (b == 0) ? o0 : o1;
#endif
    // randint span=1024 divides 2^16 -> multiplier term = 0 -> idx = bits % 1024
    atomicAdd(&counts[((size_t)h * BB + b) * LK + (bits & (LK - 1))], 1u);
  }
}

// ------- k2: kmean (count-weighted) + vmean — j-sliced, float4, atomic combine
// grid = (NSLICE, NH*BB + BB); tasks 0..31 = kmean[hb], 32..33 = vmean[b]
__global__ __launch_bounds__(256) void k_means(const float* __restrict__ kk,
                                               const float* __restrict__ v,
                                               const unsigned* __restrict__ counts,
                                               float* __restrict__ kmean,
                                               float* __restrict__ vmean) {
  int task = blockIdx.y, s = blockIdx.x, t = threadIdx.x;
  int d4 = t & 15, jsub = t >> 4;               // 16 float4-lanes over d, 16 j-rows
  __shared__ float4 part[16][16];               // [jsub][d4]
  float4 acc = make_float4(0.f, 0.f, 0.f, 0.f);
  if (task < NH * BB) {
    int b = task & 1;
    const unsigned* cnt = counts + (size_t)task * LK;
    const float4* kb4 = (const float4*)(kk + (size_t)b * LK * DH);
#pragma unroll
    for (int jj = 0; jj < LK / (16 * NSLICE); jj++) {   // 8 independent loads in flight
      int j = s * (LK / NSLICE) + jsub + 16 * jj;
      float c = (float)cnt[j];                  // broadcast across the 16 d4 lanes
      float4 kv = kb4[j * 16 + d4];
      acc.x += c * kv.x; acc.y += c * kv.y; acc.z += c * kv.z; acc.w += c * kv.w;
    }
  } else {
    int b = task - NH * BB;
    const float4* vb4 = (const float4*)(v + (size_t)b * LK * DH);
#pragma unroll
    for (int jj = 0; jj < LK / (16 * NSLICE); jj++) {
      int j = s * (LK / NSLICE) + jsub + 16 * jj;
      float4 kv = vb4[j * 16 + d4];
      acc.x += kv.x; acc.y += kv.y; acc.z += kv.z; acc.w += kv.w;
    }
  }
  part[jsub][d4] = acc;
  __syncthreads();
  if (t < 16) {                                 // t == d4 now
    float4 sum = part[0][t];
#pragma unroll
    for (int x = 1; x < 16; x++) {
      float4 p = part[x][t];
      sum.x += p.x; sum.y += p.y; sum.z += p.z; sum.w += p.w;
    }
    float scale = (task < NH * BB) ? (1.0f / (float)USAMP) : (1.0f / (float)LK);
    float* dst = (task < NH * BB) ? (kmean + (size_t)task * DH)
                                  : (vmean + (size_t)(task - NH * BB) * DH);
    atomicAdd(&dst[t * 4 + 0], sum.x * scale);
    atomicAdd(&dst[t * 4 + 1], sum.y * scale);
    atomicAdd(&dst[t * 4 + 2], sum.z * scale);
    atomicAdd(&dst[t * 4 + 3], sum.w * scale);
  }
}

// ------- k3: S[b,i,j] = q_i . k_j — transposed LDS, outer-product inner loop
__global__ __launch_bounds__(256) void k_scores(const float* __restrict__ q,
                                                const float* __restrict__ k,
                                                float* __restrict__ S) {
  __shared__ float Qt[DH][68];  // [d][row]; stride 68 words = 272B (16B-aligned,
  __shared__ float Kt[DH][68];  //  b128 row-reads land 2-way max = free)
  int b = blockIdx.z;
  int i0 = blockIdx.y * 64, j0 = blockIdx.x * 64;
  int t = threadIdx.x;
  const float* qb = q + ((size_t)b * LQ + i0) * DH;
  const float* kb = k + ((size_t)b * LK + j0) * DH;
#pragma unroll
  for (int rep = 0; rep < 4; rep++) {
    int lin = (rep * 256 + t) * 4;
    int r = lin >> 6, c = lin & 63;
    float4 qv = *(const float4*)(qb + (size_t)r * DH + c);
    float4 kv = *(const float4*)(kb + (size_t)r * DH + c);
    Qt[c][r] = qv.x; Qt[c + 1][r] = qv.y; Qt[c + 2][r] = qv.z; Qt[c + 3][r] = qv.w;
    Kt[c][r] = kv.x; Kt[c + 1][r] = kv.y; Kt[c + 2][r] = kv.z; Kt[c + 3][r] = kv.w;
  }
  __syncthreads();
  int tx = t & 15, ty = t >> 4;
  float acc[4][4] = {};
#pragma unroll 8
  for (int d = 0; d < DH; d++) {
    float4 av = *(const float4*)&Qt[d][ty * 4];   // 4 q-rows at this d
    float4 bv = *(const float4*)&Kt[d][tx * 4];   // 4 k-rows at this d
    acc[0][0] += av.x * bv.x; acc[0][1] += av.x * bv.y; acc[0][2] += av.x * bv.z; acc[0][3] += av.x * bv.w;
    acc[1][0] += av.y * bv.x; acc[1][1] += av.y * bv.y; acc[1][2] += av.y * bv.z; acc[1][3] += av.y * bv.w;
    acc[2][0] += av.z * bv.x; acc[2][1] += av.z * bv.y; acc[2][2] += av.z * bv.z; acc[2][3] += av.z * bv.w;
    acc[3][0] += av.w * bv.x; acc[3][1] += av.w * bv.y; acc[3][2] += av.w * bv.z; acc[3][3] += av.w * bv.w;
  }
  float* Sb = S + ((size_t)b * LQ + i0) * LK + j0;
#pragma unroll
  for (int r = 0; r < 4; r++) {
    *(float4*)(Sb + (size_t)(ty * 4 + r) * LK + tx * 4) =
        make_float4(acc[r][0], acc[r][1], acc[r][2], acc[r][3]);
  }
}

// ------- k4: M[h,b,i] = max_{sampled j} S[i,j] - q_i.kmean[h,b] — all heads, one S pass
__global__ __launch_bounds__(256) void k_M(const float* __restrict__ q,
                                           const float* __restrict__ S,
                                           const unsigned* __restrict__ counts,
                                           const float* __restrict__ kmean,
                                           float* __restrict__ M) {
  int b = blockIdx.y;
  __shared__ uint32_t mask[NH][LK / 32];  // 2 KB per-head sampled-key bitmask
  int t = threadIdx.x;
  for (int w = t; w < NH * (LK / 32); w += 256) {
    int h = w >> 5, blk = w & 31;
    const unsigned* cnt = counts + ((size_t)h * BB + b) * LK + blk * 32;
    uint32_t m = 0;
    for (int z = 0; z < 32; z++) m |= (cnt[z] != 0u ? 1u : 0u) << z;
    mask[h][blk] = m;
  }
  __syncthreads();
  int lane = t & 63, w4 = t >> 6;
  int i = blockIdx.x * 4 + w4;
  const float* Srow = S + ((size_t)b * LQ + i) * LK;
  float mx[NH];
#pragma unroll
  for (int h = 0; h < NH; h++) mx[h] = -INFINITY;
  for (int j = lane; j < LK; j += 64) {
    float s = Srow[j];
#pragma unroll
    for (int h = 0; h < NH; h++) {
      bool on = (mask[h][j >> 5] >> (j & 31)) & 1u;
      mx[h] = fmaxf(mx[h], on ? s : -INFINITY);
    }
  }
#pragma unroll
  for (int h = 0; h < NH; h++) {
#pragma unroll
    for (int off = 32; off > 0; off >>= 1) mx[h] = fmaxf(mx[h], __shfl_xor(mx[h], off));
  }
  float qv = q[((size_t)b * LQ + i) * DH + lane];  // lane == d (DH==64)
#pragma unroll
  for (int h = 0; h < NH; h++) {
    float p = qv * kmean[((size_t)h * BB + b) * DH + lane];
#pragma unroll
    for (int off = 32; off > 0; off >>= 1) p += __shfl_xor(p, off);
    mx[h] -= p;
  }
  if (lane == 0) {
#pragma unroll
    for (int h = 0; h < NH; h++) M[((size_t)h * BB + b) * LQ + i] = mx[h];
  }
}

// ---------------- k5: top-34 per (h,b) — shfl-based argmax, 2 barriers/iter ----
__global__ __launch_bounds__(256) void k_topk(const float* __restrict__ M,
                                              int* __restrict__ topidx) {
  int hb = blockIdx.x, t = threadIdx.x;
  __shared__ float vals[LQ];
  __shared__ float wv[4];
  __shared__ int   wi[4];
  for (int i = t; i < LQ; i += 256) vals[i] = M[(size_t)hb * LQ + i];
  __syncthreads();
  int lane = t & 63, w = t >> 6;
  for (int u = 0; u < USEL; u++) {
    float bv = -INFINITY; int bi = 0x7fffffff;
#pragma unroll
    for (int r = 0; r < 4; r++) {     // ascending idx + strict '>' => lowest idx on tie
      int i = r * 256 + t;
      float x = vals[i];
      if (x > bv) { bv = x; bi = i; }
    }
#pragma unroll
    for (int off = 32; off > 0; off >>= 1) {
      float ov = __shfl_xor(bv, off);
      int   oi = __shfl_xor(bi, off);
      if (ov > bv || (ov == bv && oi < bi)) { bv = ov; bi = oi; }
    }
    if (lane == 0) { wv[w] = bv; wi[w] = bi; }
    __syncthreads();
    if (t == 0) {
      float fv = wv[0]; int fi = wi[0];
#pragma unroll
      for (int x = 1; x < 4; x++)
        if (wv[x] > fv || (wv[x] == fv && wi[x] < fi)) { fv = wv[x]; fi = wi[x]; }
      topidx[hb * USEL + u] = fi;
      vals[fi] = -INFINITY;
    }
    __syncthreads();
  }
}

// ------- k6: softmax(S_row/32) @ v for selected rows; delta = s1 - vmean ------
__global__ __launch_bounds__(256) void k_attn(const float* __restrict__ S,
                                              const float* __restrict__ v,
                                              const int* __restrict__ topidx,
                                              const float* __restrict__ vmean,
                                              float* __restrict__ delta) {
  int hb = blockIdx.y, u = blockIdx.x;
  int b = hb % BB;
  int t = threadIdx.x, lane = t & 63, w = t >> 6;
  __shared__ float p[LK];
  __shared__ float wred[4];
  __shared__ float wred2[4];
  __shared__ float part[4][DH];
  int i = topidx[hb * USEL + u];
  const float* Srow = S + ((size_t)b * LQ + i) * LK;
  float lmx = -INFINITY;
#pragma unroll
  for (int r = 0; r < 4; r++) {
    int j = r * 256 + t;
    float x = Srow[j] * 0.03125f;   // 1/sqrt(1024) = 1/32 exactly
    p[j] = x;
    lmx = fmaxf(lmx, x);
  }
#pragma unroll
  for (int off = 32; off > 0; off >>= 1) lmx = fmaxf(lmx, __shfl_xor(lmx, off));
  if (lane == 0) wred[w] = lmx;
  __syncthreads();
  float mx = fmaxf(fmaxf(wred[0], wred[1]), fmaxf(wred[2], wred[3]));
  float lsum = 0.f;
#pragma unroll
  for (int r = 0; r < 4; r++) {
    int j = r * 256 + t;
    float e = expf(p[j] - mx);
    p[j] = e;
    lsum += e;
  }
#pragma unroll
  for (int off = 32; off > 0; off >>= 1) lsum += __shfl_xor(lsum, off);
  if (lane == 0) wred2[w] = lsum;
  __syncthreads();                  // p[] final + wred2 visible
  int d = lane, g = w;
  const float* vb = v + (size_t)b * LK * DH;
  float acc = 0.f;
  for (int j = g; j < LK; j += 4) acc += p[j] * vb[(size_t)j * DH + d];
  part[g][d] = acc;
  __syncthreads();
  if (t < DH) {
    float inv = 1.0f / (wred2[0] + wred2[1] + wred2[2] + wred2[3]);
    float s1 = (part[0][t] + part[1][t] + part[2][t] + part[3][t]) * inv;
    delta[((size_t)hb * USEL + u) * DH + t] = s1 - vmean[b * DH + t];
  }
}

// ---------------- k7: base[b,o] = sum_j tile(vmean)[j] * W[j,o] ----------------
__global__ __launch_bounds__(256) void k_base(const float* __restrict__ W,
                                              const float* __restrict__ vmean,
                                              float* __restrict__ base) {
  __shared__ float vm[DH];
  int b = blockIdx.y, hc = blockIdx.z;
  int o = blockIdx.x * 256 + threadIdx.x;
  if (threadIdx.x < DH) vm[threadIdx.x] = vmean[b * DH + threadIdx.x];
  __syncthreads();
  const float* Wr = W + (size_t)hc * DH * DM + o;
  float acc = 0.f;
#pragma unroll
  for (int d = 0; d < DH; d++) acc += vm[d] * Wr[(size_t)d * DM];
  atomicAdd(&base[b * DM + o], acc);
}

// ---------------- k8a: out[b,i,:] = base[b,:] + bproj  (dense fill) ----------------
__global__ __launch_bounds__(256) void k_fill(const float* __restrict__ base,
                                              const float* __restrict__ bproj,
                                              float* __restrict__ out) {
  int idx = blockIdx.x * 256 + threadIdx.x;        // float4 index
  int o4 = idx & (DM / 4 - 1);
  int b = idx >> 18;                               // idx / (LQ*DM/4)
  float4 bs = ((const float4*)base)[b * (DM / 4) + o4];
  float4 bp = ((const float4*)bproj)[o4];
  ((float4*)out)[idx] = make_float4(bs.x + bp.x, bs.y + bp.y, bs.z + bp.z, bs.w + bp.w);
}

// ------- k8b: one block per selected (h,b,u): out[b,i,:] += delta @ W_h ------
__global__ __launch_bounds__(256) void k_corr(const float* __restrict__ W,
                                              const int* __restrict__ topidx,
                                              const float* __restrict__ delta,
                                              float* __restrict__ out) {
  int u = blockIdx.x, hb = blockIdx.y;             // hb = h*BB + b
  int h = hb >> 1, b = hb & 1;
  int t = threadIdx.x;
  __shared__ float dl[DH];
  int i = topidx[hb * USEL + u];
  if (t < DH) dl[t] = delta[((size_t)hb * USEL + u) * DH + t];
  __syncthreads();
  const float* Wh = W + (size_t)h * DH * DM;
  float* orow = out + ((size_t)b * LQ + i) * DM;
#pragma unroll
  for (int rep = 0; rep < 4; rep++) {
    int o = rep * 256 + t;
    float acc = 0.f;
#pragma unroll 16
    for (int d = 0; d < DH; d++) acc += dl[d] * Wh[(size_t)d * DM + o];
    atomicAdd(&orow[o], acc);                       // heads may share a row
  }
}

// ---------------- host ----------------
extern "C" void kernel_launch(void* const* d_in, const int* in_sizes, int n_in,
                              void* d_out, int out_size, void* d_ws, size_t ws_size,
                              hipStream_t stream) {
  const float* q  = (const float*)d_in[0];
  const float* k  = (const float*)d_in[1];
  const float* v  = (const float*)d_in[2];
  const float* W  = (const float*)d_in[3];
  const float* bp = (const float*)d_in[4];
  float* out = (float*)d_out;

  // S lives in d_out (8 MB): consumed by k_M/k_attn before k_fill overwrites it.
  float* S = out;

  // zeroed region: counts, base, kmean, vmean (atomic-accumulated buffers)
  char* w = (char*)d_ws;
  unsigned* counts = (unsigned*)w;            w += (size_t)NH * BB * LK * 4;        // 128 KB
  float*    base   = (float*)w;               w += (size_t)BB * DM * 4;             // 8 KB
  float*    kmean  = (float*)w;               w += (size_t)NH * BB * DH * 4;        // 8 KB
  float*    vmean  = (float*)w;               w += (size_t)BB * DH * 4;             // 512 B
  float*    M      = (float*)w;               w += (size_t)NH * BB * LQ * 4;        // 128 KB
  int*      topidx = (int*)w;                 w += (size_t)NH * BB * USEL * 4;      // 4.25 KB
  float*    delta  = (float*)w;               w += (size_t)NH * BB * USEL * DH * 4; // 272 KB
  if ((size_t)(w - (char*)d_ws) > ws_size) return;

  const int ZW = NH * BB * LK + BB * DM + NH * BB * DH + BB * DH;  // u32 words to zero
  k_zero  <<<(ZW + 255) / 256, 256, 0, stream>>>(counts, ZW);
  k_sample<<<dim3((USAMP + 255) / 256, NH), 256, 0, stream>>>(counts);
  k_means <<<dim3(NSLICE, NH * BB + BB), 256, 0, stream>>>(k, v, counts, kmean, vmean);
  k_scores<<<dim3(LK / 64, LQ / 64, BB), 256, 0, stream>>>(q, k, S);
  k_M     <<<dim3(LQ / 4, BB), 256, 0, stream>>>(q, S, counts, kmean, M);
  k_topk  <<<NH * BB, 256, 0, stream>>>(M, topidx);
  k_attn  <<<dim3(USEL, NH * BB), 256, 0, stream>>>(S, v, topidx, vmean, delta);
  k_base  <<<dim3(DM / 256, BB, NH), 256, 0, stream>>>(W, vmean, base);
  k_fill  <<<(BB * LQ * DM / 4) / 256, 256, 0, stream>>>(base, bp, out);
  k_corr  <<<dim3(USEL, NH * BB), 256, 0, stream>>>(W, topidx, delta, out);
}

// Round 8
// 176.967 us; speedup vs baseline: 1.8438x; 1.2415x over previous
//
#include <hip/hip_runtime.h>
#include <math.h>
#include <stdint.h>
#include <stddef.h>

// ProbSparse multi-head attention (Informer-style), fp32, MI355X.
// Heads share q,k,v; only the threefry-sampled key set differs per head.
// S (the shared 2x1024x1024 score matrix) lives in d_out and is consumed
// (k_M, k_smax, k_pv) before k_fill/k_corr overwrite d_out with the result.

#define BB     2
#define LQ     1024
#define LK     1024
#define DH     64
#define NH     16
#define DM     1024
#define USEL   34
#define USAMP  7097
#define NSLICE 8   // j-dimension slices in k_means
#define NJ     8   // j-dimension slices in k_pv
#define JS     (LK / NJ)   // 128

#define THREEFRY_PARTITIONABLE 1

// ---------------- threefry2x32 (matches jax._src.prng) ----------------
__device__ __forceinline__ uint32_t rotl32(uint32_t x, int d) {
  return (x << d) | (x >> (32 - d));
}

__device__ __forceinline__ void threefry2x32(uint32_t k0, uint32_t k1,
                                             uint32_t x0, uint32_t x1,
                                             uint32_t& o0, uint32_t& o1) {
  uint32_t ks2 = k0 ^ k1 ^ 0x1BD11BDAu;
  x0 += k0; x1 += k1;
#define TFR(r) { x0 += x1; x1 = rotl32(x1, (r)); x1 ^= x0; }
  TFR(13) TFR(15) TFR(26) TFR(6)
  x0 += k1; x1 += ks2 + 1u;
  TFR(17) TFR(29) TFR(16) TFR(24)
  x0 += ks2; x1 += k0 + 2u;
  TFR(13) TFR(15) TFR(26) TFR(6)
  x0 += k0; x1 += k1 + 3u;
  TFR(17) TFR(29) TFR(16) TFR(24)
  x0 += k1; x1 += ks2 + 4u;
  TFR(13) TFR(15) TFR(26) TFR(6)
  x0 += ks2; x1 += k0 + 5u;
#undef TFR
  o0 = x0; o1 = x1;
}

// ---------------- k0: zero counts/base/kmean/vmean/delta_raw ----------------
__global__ void k_zero(unsigned* __restrict__ p, int n) {
  int i = blockIdx.x * blockDim.x + threadIdx.x;
  if (i < n) p[i] = 0u;
}

// ---------------- k1: sample key indices, histogram counts ----------------
__global__ void k_sample(unsigned* __restrict__ counts) {
  __shared__ uint32_t sk[2];
  int h = blockIdx.y;
  if (threadIdx.x == 0) {
    uint32_t hk0, hk1, t0, t1;
#if THREEFRY_PARTITIONABLE
    threefry2x32(0u, 42u, 0u, (uint32_t)h, hk0, hk1);   // head_keys = split (foldlike)
    threefry2x32(hk0, hk1, 0u, 1u, t0, t1);             // k2 = split(head_key)[1]
    sk[0] = t0; sk[1] = t1;
#else
    uint32_t a0, a1, b0, b1, c0, c1;
    int i0 = 2 * h, i1 = 2 * h + 1;
    if (i0 < 16) { threefry2x32(0u, 42u, (uint32_t)i0, (uint32_t)(i0 + 16), a0, a1); hk0 = a0; }
    else         { threefry2x32(0u, 42u, (uint32_t)(i0 - 16), (uint32_t)i0, a0, a1); hk0 = a1; }
    if (i1 < 16) { threefry2x32(0u, 42u, (uint32_t)i1, (uint32_t)(i1 + 16), a0, a1); hk1 = a0; }
    else         { threefry2x32(0u, 42u, (uint32_t)(i1 - 16), (uint32_t)i1, a0, a1); hk1 = a1; }
    threefry2x32(hk0, hk1, 0u, 2u, b0, b1);
    threefry2x32(hk0, hk1, 1u, 3u, c0, c1);
    sk[0] = b1; sk[1] = c1;
#endif
  }
  __syncthreads();
  int j = blockIdx.x * blockDim.x + threadIdx.x;
  if (j >= USAMP) return;
  for (int b = 0; b < BB; b++) {
    uint32_t o0, o1, bits;
#if THREEFRY_PARTITIONABLE
    threefry2x32(sk[0], sk[1], 0u, (uint32_t)(b * USAMP + j), o0, o1);
    bits = o0 ^ o1;
#else
    threefry2x32(sk[0], sk[1], (uint32_t)j, (uint32_t)(j + USAMP), o0, o1);
    bits = (b == 0) ? o0 : o1;
#endif
    // randint span=1024 divides 2^16 -> multiplier term = 0 -> idx = bits % 1024
    atomicAdd(&counts[((size_t)h * BB + b) * LK + (bits & (LK - 1))], 1u);
  }
}

// ------- k2: kmean (count-weighted) + vmean — j-sliced, float4, atomic combine
__global__ __launch_bounds__(256) void k_means(const float* __restrict__ kk,
                                               const float* __restrict__ v,
                                               const unsigned* __restrict__ counts,
                                               float* __restrict__ kmean,
                                               float* __restrict__ vmean) {
  int task = blockIdx.y, s = blockIdx.x, t = threadIdx.x;
  int d4 = t & 15, jsub = t >> 4;               // 16 float4-lanes over d, 16 j-rows
  __shared__ float4 part[16][16];               // [jsub][d4]
  float4 acc = make_float4(0.f, 0.f, 0.f, 0.f);
  if (task < NH * BB) {
    int b = task & 1;
    const unsigned* cnt = counts + (size_t)task * LK;
    const float4* kb4 = (const float4*)(kk + (size_t)b * LK * DH);
#pragma unroll
    for (int jj = 0; jj < LK / (16 * NSLICE); jj++) {   // 8 independent loads in flight
      int j = s * (LK / NSLICE) + jsub + 16 * jj;
      float c = (float)cnt[j];
      float4 kv = kb4[j * 16 + d4];
      acc.x += c * kv.x; acc.y += c * kv.y; acc.z += c * kv.z; acc.w += c * kv.w;
    }
  } else {
    int b = task - NH * BB;
    const float4* vb4 = (const float4*)(v + (size_t)b * LK * DH);
#pragma unroll
    for (int jj = 0; jj < LK / (16 * NSLICE); jj++) {
      int j = s * (LK / NSLICE) + jsub + 16 * jj;
      float4 kv = vb4[j * 16 + d4];
      acc.x += kv.x; acc.y += kv.y; acc.z += kv.z; acc.w += kv.w;
    }
  }
  part[jsub][d4] = acc;
  __syncthreads();
  if (t < 16) {
    float4 sum = part[0][t];
#pragma unroll
    for (int x = 1; x < 16; x++) {
      float4 p = part[x][t];
      sum.x += p.x; sum.y += p.y; sum.z += p.z; sum.w += p.w;
    }
    float scale = (task < NH * BB) ? (1.0f / (float)USAMP) : (1.0f / (float)LK);
    float* dst = (task < NH * BB) ? (kmean + (size_t)task * DH)
                                  : (vmean + (size_t)(task - NH * BB) * DH);
    atomicAdd(&dst[t * 4 + 0], sum.x * scale);
    atomicAdd(&dst[t * 4 + 1], sum.y * scale);
    atomicAdd(&dst[t * 4 + 2], sum.z * scale);
    atomicAdd(&dst[t * 4 + 3], sum.w * scale);
  }
}

// ------- k3: S[b,i,j] = q_i . k_j — transposed LDS, outer-product inner loop
__global__ __launch_bounds__(256) void k_scores(const float* __restrict__ q,
                                                const float* __restrict__ k,
                                                float* __restrict__ S) {
  __shared__ float Qt[DH][68];
  __shared__ float Kt[DH][68];
  int b = blockIdx.z;
  int i0 = blockIdx.y * 64, j0 = blockIdx.x * 64;
  int t = threadIdx.x;
  const float* qb = q + ((size_t)b * LQ + i0) * DH;
  const float* kb = k + ((size_t)b * LK + j0) * DH;
#pragma unroll
  for (int rep = 0; rep < 4; rep++) {
    int lin = (rep * 256 + t) * 4;
    int r = lin >> 6, c = lin & 63;
    float4 qv = *(const float4*)(qb + (size_t)r * DH + c);
    float4 kv = *(const float4*)(kb + (size_t)r * DH + c);
    Qt[c][r] = qv.x; Qt[c + 1][r] = qv.y; Qt[c + 2][r] = qv.z; Qt[c + 3][r] = qv.w;
    Kt[c][r] = kv.x; Kt[c + 1][r] = kv.y; Kt[c + 2][r] = kv.z; Kt[c + 3][r] = kv.w;
  }
  __syncthreads();
  int tx = t & 15, ty = t >> 4;
  float acc[4][4] = {};
#pragma unroll 8
  for (int d = 0; d < DH; d++) {
    float4 av = *(const float4*)&Qt[d][ty * 4];
    float4 bv = *(const float4*)&Kt[d][tx * 4];
    acc[0][0] += av.x * bv.x; acc[0][1] += av.x * bv.y; acc[0][2] += av.x * bv.z; acc[0][3] += av.x * bv.w;
    acc[1][0] += av.y * bv.x; acc[1][1] += av.y * bv.y; acc[1][2] += av.y * bv.z; acc[1][3] += av.y * bv.w;
    acc[2][0] += av.z * bv.x; acc[2][1] += av.z * bv.y; acc[2][2] += av.z * bv.z; acc[2][3] += av.z * bv.w;
    acc[3][0] += av.w * bv.x; acc[3][1] += av.w * bv.y; acc[3][2] += av.w * bv.z; acc[3][3] += av.w * bv.w;
  }
  float* Sb = S + ((size_t)b * LQ + i0) * LK + j0;
#pragma unroll
  for (int r = 0; r < 4; r++) {
    *(float4*)(Sb + (size_t)(ty * 4 + r) * LK + tx * 4) =
        make_float4(acc[r][0], acc[r][1], acc[r][2], acc[r][3]);
  }
}

// ------- k4: M[h,b,i] = max_{sampled j} S[i,j] - q_i.kmean[h,b] — all heads, one S pass
__global__ __launch_bounds__(256) void k_M(const float* __restrict__ q,
                                           const float* __restrict__ S,
                                           const unsigned* __restrict__ counts,
                                           const float* __restrict__ kmean,
                                           float* __restrict__ M) {
  int b = blockIdx.y;
  __shared__ uint32_t mask[NH][LK / 32];
  int t = threadIdx.x;
  for (int w = t; w < NH * (LK / 32); w += 256) {
    int h = w >> 5, blk = w & 31;
    const unsigned* cnt = counts + ((size_t)h * BB + b) * LK + blk * 32;
    uint32_t m = 0;
    for (int z = 0; z < 32; z++) m |= (cnt[z] != 0u ? 1u : 0u) << z;
    mask[h][blk] = m;
  }
  __syncthreads();
  int lane = t & 63, w4 = t >> 6;
  int i = blockIdx.x * 4 + w4;
  const float* Srow = S + ((size_t)b * LQ + i) * LK;
  float mx[NH];
#pragma unroll
  for (int h = 0; h < NH; h++) mx[h] = -INFINITY;
  for (int j = lane; j < LK; j += 64) {
    float s = Srow[j];
#pragma unroll
    for (int h = 0; h < NH; h++) {
      bool on = (mask[h][j >> 5] >> (j & 31)) & 1u;
      mx[h] = fmaxf(mx[h], on ? s : -INFINITY);
    }
  }
#pragma unroll
  for (int h = 0; h < NH; h++) {
#pragma unroll
    for (int off = 32; off > 0; off >>= 1) mx[h] = fmaxf(mx[h], __shfl_xor(mx[h], off));
  }
  float qv = q[((size_t)b * LQ + i) * DH + lane];  // lane == d (DH==64)
#pragma unroll
  for (int h = 0; h < NH; h++) {
    float p = qv * kmean[((size_t)h * BB + b) * DH + lane];
#pragma unroll
    for (int off = 32; off > 0; off >>= 1) p += __shfl_xor(p, off);
    mx[h] -= p;
  }
  if (lane == 0) {
#pragma unroll
    for (int h = 0; h < NH; h++) M[((size_t)h * BB + b) * LQ + i] = mx[h];
  }
}

// ---------------- k5: top-34 per (h,b) — shfl-based argmax ----------------
__global__ __launch_bounds__(256) void k_topk(const float* __restrict__ M,
                                              int* __restrict__ topidx) {
  int hb = blockIdx.x, t = threadIdx.x;
  __shared__ float vals[LQ];
  __shared__ float wv[4];
  __shared__ int   wi[4];
  for (int i = t; i < LQ; i += 256) vals[i] = M[(size_t)hb * LQ + i];
  __syncthreads();
  int lane = t & 63, w = t >> 6;
  for (int u = 0; u < USEL; u++) {
    float bv = -INFINITY; int bi = 0x7fffffff;
#pragma unroll
    for (int r = 0; r < 4; r++) {     // ascending idx + strict '>' => lowest idx on tie
      int i = r * 256 + t;
      float x = vals[i];
      if (x > bv) { bv = x; bi = i; }
    }
#pragma unroll
    for (int off = 32; off > 0; off >>= 1) {
      float ov = __shfl_xor(bv, off);
      int   oi = __shfl_xor(bi, off);
      if (ov > bv || (ov == bv && oi < bi)) { bv = ov; bi = oi; }
    }
    if (lane == 0) { wv[w] = bv; wi[w] = bi; }
    __syncthreads();
    if (t == 0) {
      float fv = wv[0]; int fi = wi[0];
#pragma unroll
      for (int x = 1; x < 4; x++)
        if (wv[x] > fv || (wv[x] == fv && wi[x] < fi)) { fv = wv[x]; fi = wi[x]; }
      topidx[hb * USEL + u] = fi;
      vals[fi] = -INFINITY;
    }
    __syncthreads();
  }
}

// ------- k6a: per selected row — softmax max + expsum (S row held in regs) ------
__global__ __launch_bounds__(256) void k_smax(const float* __restrict__ S,
                                              const int* __restrict__ topidx,
                                              float* __restrict__ smax,
                                              float* __restrict__ ssum) {
  int hb = blockIdx.y, u = blockIdx.x, b = hb & 1;
  int t = threadIdx.x, lane = t & 63, w = t >> 6;
  __shared__ float wred[4], wred2[4];
  int i = topidx[hb * USEL + u];
  const float* Srow = S + ((size_t)b * LQ + i) * LK;
  float x[4], lmx = -INFINITY;
#pragma unroll
  for (int r = 0; r < 4; r++) {
    x[r] = Srow[r * 256 + t] * 0.03125f;   // 1/sqrt(1024) = 1/32 exactly
    lmx = fmaxf(lmx, x[r]);
  }
#pragma unroll
  for (int off = 32; off > 0; off >>= 1) lmx = fmaxf(lmx, __shfl_xor(lmx, off));
  if (lane == 0) wred[w] = lmx;
  __syncthreads();
  float mx = fmaxf(fmaxf(wred[0], wred[1]), fmaxf(wred[2], wred[3]));
  float ls = expf(x[0] - mx) + expf(x[1] - mx) + expf(x[2] - mx) + expf(x[3] - mx);
#pragma unroll
  for (int off = 32; off > 0; off >>= 1) ls += __shfl_xor(ls, off);
  if (lane == 0) wred2[w] = ls;
  __syncthreads();
  if (t == 0) {
    smax[hb * USEL + u] = mx;
    ssum[hb * USEL + u] = wred2[0] + wred2[1] + wred2[2] + wred2[3];
  }
}

// ------- k6b: PV j-sliced — delta_raw[hb,u,:] += sum_{j in slice} p * v[j,:] ------
// grid (NJ, NH*BB). LDS-staged p, register-staged v (32 loads in flight/thread).
__global__ __launch_bounds__(256) void k_pv(const float* __restrict__ S,
                                            const float* __restrict__ v,
                                            const int* __restrict__ topidx,
                                            const float* __restrict__ smax,
                                            float* __restrict__ delta_raw) {
  int hb = blockIdx.y, s = blockIdx.x, b = hb & 1;
  int t = threadIdx.x, d = t & 63, g = t >> 6;
  __shared__ float p[USEL][JS];        // 17 KB
  __shared__ float part[4][USEL][DH];  // 34.8 KB
  for (int idx = t; idx < USEL * JS; idx += 256) {
    int u = idx >> 7, jj = idx & (JS - 1);
    int i = topidx[hb * USEL + u];
    float xs = S[((size_t)b * LQ + i) * LK + s * JS + jj];
    p[u][jj] = expf(xs * 0.03125f - smax[hb * USEL + u]);
  }
  __syncthreads();
  // each wave owns 32 contiguous jj; v values held in registers
  float vreg[32];
  const float* vb = v + ((size_t)b * LK + s * JS + g * 32) * DH + d;
#pragma unroll
  for (int jj = 0; jj < 32; jj++) vreg[jj] = vb[(size_t)jj * DH];
  for (int u = 0; u < USEL; u++) {
    float acc = 0.f;
#pragma unroll
    for (int j4 = 0; j4 < 8; j4++) {
      float4 pp = *(const float4*)&p[u][g * 32 + j4 * 4];   // wave-uniform: broadcast
      acc += pp.x * vreg[j4 * 4] + pp.y * vreg[j4 * 4 + 1] +
             pp.z * vreg[j4 * 4 + 2] + pp.w * vreg[j4 * 4 + 3];
    }
    part[g][u][d] = acc;
  }
  __syncthreads();
  for (int idx = t; idx < USEL * DH; idx += 256) {
    int u = idx >> 6, dd = idx & 63;
    float sum = part[0][u][dd] + part[1][u][dd] + part[2][u][dd] + part[3][u][dd];
    atomicAdd(&delta_raw[((size_t)hb * USEL + u) * DH + dd], sum);
  }
}

// ---------------- k7: base[b,o] = sum_j tile(vmean)[j] * W[j,o] ----------------
__global__ __launch_bounds__(256) void k_base(const float* __restrict__ W,
                                              const float* __restrict__ vmean,
                                              float* __restrict__ base) {
  __shared__ float vm[DH];
  int b = blockIdx.y, hc = blockIdx.z;
  int o = blockIdx.x * 256 + threadIdx.x;
  if (threadIdx.x < DH) vm[threadIdx.x] = vmean[b * DH + threadIdx.x];
  __syncthreads();
  const float* Wr = W + (size_t)hc * DH * DM + o;
  float acc = 0.f;
#pragma unroll
  for (int d = 0; d < DH; d++) acc += vm[d] * Wr[(size_t)d * DM];
  atomicAdd(&base[b * DM + o], acc);
}

// ---------------- k8a: out[b,i,:] = base[b,:] + bproj  (dense fill) ----------------
__global__ __launch_bounds__(256) void k_fill(const float* __restrict__ base,
                                              const float* __restrict__ bproj,
                                              float* __restrict__ out) {
  int idx = blockIdx.x * 256 + threadIdx.x;        // float4 index
  int o4 = idx & (DM / 4 - 1);
  int b = idx >> 18;
  float4 bs = ((const float4*)base)[b * (DM / 4) + o4];
  float4 bp = ((const float4*)bproj)[o4];
  ((float4*)out)[idx] = make_float4(bs.x + bp.x, bs.y + bp.y, bs.z + bp.z, bs.w + bp.w);
}

// ------- k8b: one block per selected (h,b,u): out[b,i,:] += (raw/sum - vmean) @ W_h
__global__ __launch_bounds__(256) void k_corr(const float* __restrict__ W,
                                              const int* __restrict__ topidx,
                                              const float* __restrict__ delta_raw,
                                              const float* __restrict__ ssum,
                                              const float* __restrict__ vmean,
                                              float* __restrict__ out) {
  int u = blockIdx.x, hb = blockIdx.y;             // hb = h*BB + b
  int h = hb >> 1, b = hb & 1;
  int t = threadIdx.x;
  __shared__ float dl[DH];
  int i = topidx[hb * USEL + u];
  if (t < DH) {
    float inv = 1.0f / ssum[hb * USEL + u];
    dl[t] = delta_raw[((size_t)hb * USEL + u) * DH + t] * inv - vmean[b * DH + t];
  }
  __syncthreads();
  const float* Wh = W + (size_t)h * DH * DM;
  float* orow = out + ((size_t)b * LQ + i) * DM;
#pragma unroll
  for (int rep = 0; rep < 4; rep++) {
    int o = rep * 256 + t;
    float acc = 0.f;
#pragma unroll 16
    for (int d = 0; d < DH; d++) acc += dl[d] * Wh[(size_t)d * DM + o];
    atomicAdd(&orow[o], acc);                       // heads may share a row
  }
}

// ---------------- host ----------------
extern "C" void kernel_launch(void* const* d_in, const int* in_sizes, int n_in,
                              void* d_out, int out_size, void* d_ws, size_t ws_size,
                              hipStream_t stream) {
  const float* q  = (const float*)d_in[0];
  const float* k  = (const float*)d_in[1];
  const float* v  = (const float*)d_in[2];
  const float* W  = (const float*)d_in[3];
  const float* bp = (const float*)d_in[4];
  float* out = (float*)d_out;

  // S lives in d_out (8 MB): consumed by k_M/k_smax/k_pv before k_fill overwrites it.
  float* S = out;

  // zeroed region: counts, base, kmean, vmean, delta_raw (atomic-accumulated)
  char* w = (char*)d_ws;
  unsigned* counts    = (unsigned*)w;         w += (size_t)NH * BB * LK * 4;          // 128 KB
  float*    base      = (float*)w;            w += (size_t)BB * DM * 4;               // 8 KB
  float*    kmean     = (float*)w;            w += (size_t)NH * BB * DH * 4;          // 8 KB
  float*    vmean     = (float*)w;            w += (size_t)BB * DH * 4;               // 512 B
  float*    delta_raw = (float*)w;            w += (size_t)NH * BB * USEL * DH * 4;   // 272 KB
  float*    M         = (float*)w;            w += (size_t)NH * BB * LQ * 4;          // 128 KB
  int*      topidx    = (int*)w;              w += (size_t)NH * BB * USEL * 4;        // 4.25 KB
  float*    smax      = (float*)w;            w += (size_t)NH * BB * USEL * 4;        // 4.25 KB
  float*    ssum      = (float*)w;            w += (size_t)NH * BB * USEL * 4;        // 4.25 KB
  if ((size_t)(w - (char*)d_ws) > ws_size) return;

  const int ZW = NH * BB * LK + BB * DM + NH * BB * DH + BB * DH + NH * BB * USEL * DH;
  k_zero  <<<(ZW + 255) / 256, 256, 0, stream>>>(counts, ZW);
  k_sample<<<dim3((USAMP + 255) / 256, NH), 256, 0, stream>>>(counts);
  k_means <<<dim3(NSLICE, NH * BB + BB), 256, 0, stream>>>(k, v, counts, kmean, vmean);
  k_scores<<<dim3(LK / 64, LQ / 64, BB), 256, 0, stream>>>(q, k, S);
  k_M     <<<dim3(LQ / 4, BB), 256, 0, stream>>>(q, S, counts, kmean, M);
  k_topk  <<<NH * BB, 256, 0, stream>>>(M, topidx);
  k_smax  <<<dim3(USEL, NH * BB), 256, 0, stream>>>(S, topidx, smax, ssum);
  k_pv    <<<dim3(NJ, NH * BB), 256, 0, stream>>>(S, v, topidx, smax, delta_raw);
  k_base  <<<dim3(DM / 256, BB, NH), 256, 0, stream>>>(W, vmean, base);
  k_fill  <<<(BB * LQ * DM / 4) / 256, 256, 0, stream>>>(base, bp, out);
  k_corr  <<<dim3(USEL, NH * BB), 256, 0, stream>>>(W, topidx, delta_raw, ssum, vmean, out);
}